// Round 2
// baseline (333.118 us; speedup 1.0000x reference)
//
#include <hip/hip_runtime.h>
#include <hip/hip_bf16.h>

typedef __bf16 bf16x8 __attribute__((ext_vector_type(8)));
typedef float f32x4 __attribute__((ext_vector_type(4)));
typedef unsigned short u16;
typedef unsigned long long u64;

#define QSCALE 0.18033688011112042f  /* log2(e)/8 : folds SCALE and exp->exp2 into Q */

__device__ __forceinline__ u16 f2b(float x) {
  __hip_bfloat16 h = __float2bfloat16(x);
  return __builtin_bit_cast(u16, h);
}

__device__ __forceinline__ float exp2_fast(float x) {
#if __has_builtin(__builtin_amdgcn_exp2f)
  return __builtin_amdgcn_exp2f(x);
#else
  float r; asm("v_exp_f32 %0, %1" : "=v"(r) : "v"(x)); return r;
#endif
}

// ---------------- cast f32 -> bf16 (4 elems/thread) ----------------
__global__ __launch_bounds__(256) void cast_bf16_kernel(const float* __restrict__ src,
                                                        u16* __restrict__ dst, int n4) {
  int i = blockIdx.x * 256 + threadIdx.x;
  if (i >= n4) return;
  float4 v = ((const float4*)src)[i];
  ushort4 o;
  o.x = f2b(v.x); o.y = f2b(v.y); o.z = f2b(v.z); o.w = f2b(v.w);
  ((ushort4*)dst)[i] = o;
}

// ---------------- transpose+cast: src [R][C] f32 -> dst [C][R] bf16 ----------------
__global__ __launch_bounds__(256) void transpose_cast_kernel(const float* __restrict__ src,
                                                             u16* __restrict__ dst,
                                                             int R, int C) {
  __shared__ float t[32][33];
  int c0 = blockIdx.x * 32, r0 = blockIdx.y * 32;
  int tx = threadIdx.x, ty = threadIdx.y;
  for (int k = 0; k < 32; k += 8)
    t[ty + k][tx] = src[(size_t)(r0 + ty + k) * C + c0 + tx];
  __syncthreads();
  for (int k = 0; k < 32; k += 8)
    dst[(size_t)(c0 + ty + k) * R + r0 + tx] = f2b(t[tx][ty + k]);
}

// ---------------- mask [2048][2048] int32 -> bit-packed u64 words ----------------
__global__ __launch_bounds__(256) void maskbits_kernel(const int* __restrict__ mask,
                                                       u64* __restrict__ bits) {
  int gtid = blockIdx.x * 256 + threadIdx.x;
  int wid = gtid >> 6, lane = gtid & 63;
  int v = mask[(size_t)wid * 64 + lane];
  u64 b = __ballot(v != 0);
  if (lane == 0) bits[wid] = b;
}

// ---------------- QKV GEMM: xb[4096][1024] @ Wqkv_t[3072][1024]^T ----------------
// Epilogue scatters into Qb (pre-scaled by QSCALE) / Kb [B][H][N][64], Vt [B][H][64][N].
__global__ __launch_bounds__(256) void gemm_qkv_kernel(const u16* __restrict__ A,
                                                       const u16* __restrict__ Bt,
                                                       u16* __restrict__ Qb,
                                                       u16* __restrict__ Kb,
                                                       u16* __restrict__ Vt) {
  __shared__ u16 lA[128 * 32], lB[128 * 32];
  const int tid = threadIdx.x, lane = tid & 63, w = tid >> 6;
  const int wr = w >> 1, wc = w & 1, lrow = lane & 15, lk = lane >> 4;
  const int bm = blockIdx.y, bn = blockIdx.x;
  const int srow = tid >> 2, scol = (tid & 3) * 8;
  const u16* Arow = A + (size_t)(bm * 128 + srow) * 1024 + scol;
  const u16* Brow = Bt + (size_t)(bn * 128 + srow) * 1024 + scol;
  f32x4 acc[4][4] = {};
  for (int k0 = 0; k0 < 1024; k0 += 32) {
    uint4 a0 = *(const uint4*)(Arow + k0);
    uint4 a1 = *(const uint4*)(Arow + 64 * 1024 + k0);
    uint4 b0 = *(const uint4*)(Brow + k0);
    uint4 b1 = *(const uint4*)(Brow + 64 * 1024 + k0);
    __syncthreads();
    *(uint4*)&lA[srow * 32 + scol] = a0;
    *(uint4*)&lA[(srow + 64) * 32 + scol] = a1;
    *(uint4*)&lB[srow * 32 + scol] = b0;
    *(uint4*)&lB[(srow + 64) * 32 + scol] = b1;
    __syncthreads();
    bf16x8 af[4], bfr[4];
    for (int mi = 0; mi < 4; mi++)
      af[mi] = *(const bf16x8*)&lA[(wr * 64 + mi * 16 + lrow) * 32 + lk * 8];
    for (int ni = 0; ni < 4; ni++)
      bfr[ni] = *(const bf16x8*)&lB[(wc * 64 + ni * 16 + lrow) * 32 + lk * 8];
    for (int mi = 0; mi < 4; mi++)
      for (int ni = 0; ni < 4; ni++)
        acc[mi][ni] = __builtin_amdgcn_mfma_f32_16x16x32_bf16(af[mi], bfr[ni], acc[mi][ni], 0, 0, 0);
  }
  const int rowbase = bm * 128 + wr * 64;
  const int colbase = bn * 128 + wc * 64;
  for (int mi = 0; mi < 4; mi++)
    for (int ni = 0; ni < 4; ni++)
      for (int r = 0; r < 4; r++) {
        int row = rowbase + mi * 16 + lk * 4 + r;
        int col = colbase + ni * 16 + lrow;
        int b = row >> 11, n = row & 2047;
        int which = col >> 10, within = col & 1023;
        int h = within >> 6, d = within & 63;
        float av = acc[mi][ni][r];
        size_t bh = (size_t)(b * 16 + h);
        if (which == 0)      Qb[(bh * 2048 + n) * 64 + d] = f2b(av * QSCALE);
        else if (which == 1) Kb[(bh * 2048 + n) * 64 + d] = f2b(av);
        else                 Vt[(bh * 64 + d) * 2048 + n] = f2b(av);
      }
}

// ---------------- out-proj GEMM: attnb[4096][1024] @ Wout_t[1024][1024]^T + bias ----------------
__global__ __launch_bounds__(256) void gemm_out_kernel(const u16* __restrict__ A,
                                                       const u16* __restrict__ Bt,
                                                       const float* __restrict__ bias,
                                                       float* __restrict__ out) {
  __shared__ u16 lA[128 * 32], lB[128 * 32];
  const int tid = threadIdx.x, lane = tid & 63, w = tid >> 6;
  const int wr = w >> 1, wc = w & 1, lrow = lane & 15, lk = lane >> 4;
  const int bm = blockIdx.y, bn = blockIdx.x;
  const int srow = tid >> 2, scol = (tid & 3) * 8;
  const u16* Arow = A + (size_t)(bm * 128 + srow) * 1024 + scol;
  const u16* Brow = Bt + (size_t)(bn * 128 + srow) * 1024 + scol;
  f32x4 acc[4][4] = {};
  for (int k0 = 0; k0 < 1024; k0 += 32) {
    uint4 a0 = *(const uint4*)(Arow + k0);
    uint4 a1 = *(const uint4*)(Arow + 64 * 1024 + k0);
    uint4 b0 = *(const uint4*)(Brow + k0);
    uint4 b1 = *(const uint4*)(Brow + 64 * 1024 + k0);
    __syncthreads();
    *(uint4*)&lA[srow * 32 + scol] = a0;
    *(uint4*)&lA[(srow + 64) * 32 + scol] = a1;
    *(uint4*)&lB[srow * 32 + scol] = b0;
    *(uint4*)&lB[(srow + 64) * 32 + scol] = b1;
    __syncthreads();
    bf16x8 af[4], bfr[4];
    for (int mi = 0; mi < 4; mi++)
      af[mi] = *(const bf16x8*)&lA[(wr * 64 + mi * 16 + lrow) * 32 + lk * 8];
    for (int ni = 0; ni < 4; ni++)
      bfr[ni] = *(const bf16x8*)&lB[(wc * 64 + ni * 16 + lrow) * 32 + lk * 8];
    for (int mi = 0; mi < 4; mi++)
      for (int ni = 0; ni < 4; ni++)
        acc[mi][ni] = __builtin_amdgcn_mfma_f32_16x16x32_bf16(af[mi], bfr[ni], acc[mi][ni], 0, 0, 0);
  }
  const int rowbase = bm * 128 + wr * 64;
  const int colbase = bn * 128 + wc * 64;
  for (int mi = 0; mi < 4; mi++)
    for (int ni = 0; ni < 4; ni++)
      for (int r = 0; r < 4; r++) {
        int row = rowbase + mi * 16 + lk * 4 + r;
        int col = colbase + ni * 16 + lrow;
        out[(size_t)row * 1024 + col] = acc[mi][ni][r] + bias[col];
      }
}

// ---------------- flash attention ----------------
// grid: (N/64, B*H). 4 waves/block; wave w owns 16 q-rows. KV chunks of 64.
// S is log2-scaled (Q pre-scaled by QSCALE); mask via bit-packed words.
__global__ __launch_bounds__(256, 3) void attn_kernel(const u16* __restrict__ Qb,
                                                      const u16* __restrict__ Kb,
                                                      const u16* __restrict__ Vt,
                                                      const u64* __restrict__ Mb,
                                                      u16* __restrict__ attnb) {
  __shared__ u16 Plds[4][16 * 64];  // per-wave 16x64 P tile, XOR-swizzled rows of 128B
  const int tid = threadIdx.x, lane = tid & 63, w = tid >> 6;
  const int lrow = lane & 15, lk = lane >> 4;
  const int qt = blockIdx.x, bh = blockIdx.y;
  const int h = bh & 15, b = bh >> 4;
  const int q0 = qt * 64 + w * 16;
  const u16* Qp = Qb + (size_t)bh * 2048 * 64;
  const u16* Kp = Kb + (size_t)bh * 2048 * 64;
  const u16* Vp = Vt + (size_t)bh * 64 * 2048;
  u16* myP = &Plds[w][0];

  bf16x8 qf0 = *(const bf16x8*)&Qp[(q0 + lrow) * 64 + lk * 8];
  bf16x8 qf1 = *(const bf16x8*)&Qp[(q0 + lrow) * 64 + 32 + lk * 8];

  f32x4 acc[4] = {};
  float m[4], lpart[4];
#pragma unroll
  for (int r = 0; r < 4; r++) { m[r] = -3.0e38f; lpart[r] = 0.f; }

  // preload K frags for chunk 0
  bf16x8 kf[4][2];
#pragma unroll
  for (int jc = 0; jc < 4; jc++) {
    const u16* kb = &Kp[(jc * 16 + lrow) * 64 + lk * 8];
    kf[jc][0] = *(const bf16x8*)kb;
    kf[jc][1] = *(const bf16x8*)(kb + 32);
  }

  for (int j0 = 0; j0 < 2048; j0 += 64) {
    // V frags for current chunk — issued early, consumed after softmax
    bf16x8 vf[4][2];
#pragma unroll
    for (int dt = 0; dt < 4; dt++)
#pragma unroll
      for (int kc = 0; kc < 2; kc++)
        vf[dt][kc] = *(const bf16x8*)&Vp[(dt * 16 + lrow) * 2048 + j0 + kc * 32 + lk * 8];
    // mask words: 64 cols per row, broadcast within each 16-lane quarter
    u64 mw[4];
#pragma unroll
    for (int r = 0; r < 4; r++)
      mw[r] = Mb[(size_t)(q0 + lk * 4 + r) * 32 + (j0 >> 6)];

    // ---- QK^T: 4 16x16 S-tiles over K=64 (already log2-scaled) ----
    f32x4 s[4];
    __builtin_amdgcn_s_setprio(1);
#pragma unroll
    for (int jc = 0; jc < 4; jc++) {
      f32x4 z = {};
      z = __builtin_amdgcn_mfma_f32_16x16x32_bf16(qf0, kf[jc][0], z, 0, 0, 0);
      z = __builtin_amdgcn_mfma_f32_16x16x32_bf16(qf1, kf[jc][1], z, 0, 0, 0);
      s[jc] = z;
    }
    __builtin_amdgcn_s_setprio(0);

    // prefetch next chunk's K (latency hidden under softmax+PV)
    if (j0 + 64 < 2048) {
#pragma unroll
      for (int jc = 0; jc < 4; jc++) {
        const u16* kb = &Kp[(j0 + 64 + jc * 16 + lrow) * 64 + lk * 8];
        kf[jc][0] = *(const bf16x8*)kb;
        kf[jc][1] = *(const bf16x8*)(kb + 32);
      }
    }

    // ---- mask + per-row max ----
    float pmax[4];
#pragma unroll
    for (int r = 0; r < 4; r++) pmax[r] = -3.0e38f;
#pragma unroll
    for (int r = 0; r < 4; r++) {
      unsigned wlo = (unsigned)mw[r], whi = (unsigned)(mw[r] >> 32);
#pragma unroll
      for (int jc = 0; jc < 4; jc++) {
        unsigned half = (jc & 2) ? whi : wlo;
        int bit = (int)((half >> (((jc & 1) << 4) + lrow)) & 1u);
        float v = bit ? s[jc][r] : -1e9f;
        s[jc][r] = v;
        pmax[r] = fmaxf(pmax[r], v);
      }
    }
#pragma unroll
    for (int off = 1; off < 16; off <<= 1)
#pragma unroll
      for (int r = 0; r < 4; r++)
        pmax[r] = fmaxf(pmax[r], __shfl_xor(pmax[r], off, 64));

    // ---- deferred rescale (THR=8 in log2 domain => P bounded by 256) ----
    bool need = (pmax[0] > m[0] + 8.f) | (pmax[1] > m[1] + 8.f) |
                (pmax[2] > m[2] + 8.f) | (pmax[3] > m[3] + 8.f);
    if (__any(need)) {
#pragma unroll
      for (int r = 0; r < 4; r++) {
        float mn = fmaxf(m[r], pmax[r]);
        float f = exp2_fast(m[r] - mn);
        m[r] = mn;
        lpart[r] *= f;
#pragma unroll
        for (int dt = 0; dt < 4; dt++) acc[dt][r] *= f;
      }
    }

    // ---- P = exp2(s - m); per-lane partial sums; swizzled LDS store ----
#pragma unroll
    for (int jc = 0; jc < 4; jc++)
#pragma unroll
      for (int r = 0; r < 4; r++) {
        float p = exp2_fast(s[jc][r] - m[r]);
        lpart[r] += p;
        int row = lk * 4 + r;
        int byte = row * 128 + (((jc * 16 + lrow) * 2) ^ ((row & 7) << 4));
        *(u16*)((char*)myP + byte) = f2b(p);
      }
    asm volatile("s_waitcnt lgkmcnt(0)" ::: "memory");

    // ---- PV: A-frag from swizzled LDS P, B-frag = vf ----
    __builtin_amdgcn_s_setprio(1);
#pragma unroll
    for (int kc = 0; kc < 2; kc++) {
      int byte = lrow * 128 + ((kc * 64 + lk * 16) ^ ((lrow & 7) << 4));
      bf16x8 pf = *(const bf16x8*)((const char*)myP + byte);
#pragma unroll
      for (int dt = 0; dt < 4; dt++)
        acc[dt] = __builtin_amdgcn_mfma_f32_16x16x32_bf16(pf, vf[dt][kc], acc[dt], 0, 0, 0);
    }
    __builtin_amdgcn_s_setprio(0);
  }

  // ---- final row-sum reduce (once), divide, store ----
#pragma unroll
  for (int off = 1; off < 16; off <<= 1)
#pragma unroll
    for (int r = 0; r < 4; r++)
      lpart[r] += __shfl_xor(lpart[r], off, 64);
#pragma unroll
  for (int dt = 0; dt < 4; dt++)
#pragma unroll
    for (int r = 0; r < 4; r++) {
      float o = acc[dt][r] / lpart[r];
      int n = q0 + lk * 4 + r;
      attnb[((size_t)b * 2048 + n) * 1024 + h * 64 + dt * 16 + lrow] = f2b(o);
    }
}

extern "C" void kernel_launch(void* const* d_in, const int* in_sizes, int n_in,
                              void* d_out, int out_size, void* d_ws, size_t ws_size,
                              hipStream_t stream) {
  const float* x    = (const float*)d_in[0];
  const int*   mask = (const int*)d_in[1];
  const float* Wqkv = (const float*)d_in[2];
  const float* Wout = (const float*)d_in[3];
  const float* bout = (const float*)d_in[4];
  float* out = (float*)d_out;

  char* ws = (char*)d_ws;
  // layout (bytes): [0,8M) xb / attnb; [8M,14M) Wqkv_t, later [8M,10M) Wout_t + [10M,10.5M) maskbits;
  // [14M,22M) Qb; [22M,30M) Kb; [30M,38M) Vt
  u16* xb     = (u16*)(ws);
  u16* attnb  = xb;
  u16* Wqkv_t = (u16*)(ws + (size_t)(8u << 20));
  u16* Wout_t = Wqkv_t;
  u64* mbits  = (u64*)(ws + (size_t)(10u << 20));
  u16* Qb     = (u16*)(ws + (size_t)(14u << 20));
  u16* Kb     = (u16*)(ws + (size_t)(22u << 20));
  u16* Vt     = (u16*)(ws + (size_t)(30u << 20));

  cast_bf16_kernel<<<4096, 256, 0, stream>>>(x, xb, 4096 * 1024 / 4);
  transpose_cast_kernel<<<dim3(96, 32), dim3(32, 8), 0, stream>>>(Wqkv, Wqkv_t, 1024, 3072);
  gemm_qkv_kernel<<<dim3(24, 32), 256, 0, stream>>>(xb, Wqkv_t, Qb, Kb, Vt);
  transpose_cast_kernel<<<dim3(32, 32), dim3(32, 8), 0, stream>>>(Wout, Wout_t, 1024, 1024);
  maskbits_kernel<<<16384, 256, 0, stream>>>(mask, mbits);
  attn_kernel<<<dim3(32, 32), 256, 0, stream>>>(Qb, Kb, Vt, mbits, attnb);
  gemm_out_kernel<<<dim3(8, 32), 256, 0, stream>>>(attnb, Wout_t, bout, out);
}

// Round 4
// 217.110 us; speedup vs baseline: 1.5343x; 1.5343x over previous
//
#include <hip/hip_runtime.h>
#include <hip/hip_bf16.h>

typedef __bf16 bf16x8 __attribute__((ext_vector_type(8)));
typedef float f32x4 __attribute__((ext_vector_type(4)));
typedef float f32x16 __attribute__((ext_vector_type(16)));
typedef unsigned short u16;
typedef unsigned int u32;
typedef unsigned long long u64;
typedef u32 u32x4v __attribute__((ext_vector_type(4)));

#define QSCALE 0.18033688011112042f  /* log2(e)/8 : folds SCALE and exp->exp2 into Q */

__device__ __forceinline__ u16 f2b(float x) {
  __hip_bfloat16 h = __float2bfloat16(x);
  return __builtin_bit_cast(u16, h);
}

__device__ __forceinline__ float exp2_fast(float x) {
#if __has_builtin(__builtin_amdgcn_exp2f)
  return __builtin_amdgcn_exp2f(x);
#else
  float r; asm("v_exp_f32 %0, %1" : "=v"(r) : "v"(x)); return r;
#endif
}

// ---------------- cast f32 -> bf16 (4 elems/thread) ----------------
__global__ __launch_bounds__(256) void cast_bf16_kernel(const float* __restrict__ src,
                                                        u16* __restrict__ dst, int n4) {
  int i = blockIdx.x * 256 + threadIdx.x;
  if (i >= n4) return;
  float4 v = ((const float4*)src)[i];
  ushort4 o;
  o.x = f2b(v.x); o.y = f2b(v.y); o.z = f2b(v.z); o.w = f2b(v.w);
  ((ushort4*)dst)[i] = o;
}

// ---------------- transpose+cast: src [R][C] f32 -> dst [C][R] bf16 ----------------
__global__ __launch_bounds__(256) void transpose_cast_kernel(const float* __restrict__ src,
                                                             u16* __restrict__ dst,
                                                             int R, int C) {
  __shared__ float t[32][33];
  int c0 = blockIdx.x * 32, r0 = blockIdx.y * 32;
  int tx = threadIdx.x, ty = threadIdx.y;
  for (int k = 0; k < 32; k += 8)
    t[ty + k][tx] = src[(size_t)(r0 + ty + k) * C + c0 + tx];
  __syncthreads();
  for (int k = 0; k < 32; k += 8)
    dst[(size_t)(c0 + ty + k) * R + r0 + tx] = f2b(t[tx][ty + k]);
}

// ---------------- mask [2048][2048] int32 -> bit-packed u64 words ----------------
__global__ __launch_bounds__(256) void maskbits_kernel(const int* __restrict__ mask,
                                                       u64* __restrict__ bits) {
  int gtid = blockIdx.x * 256 + threadIdx.x;
  int wid = gtid >> 6, lane = gtid & 63;
  int v = mask[(size_t)wid * 64 + lane];
  u64 b = __ballot(v != 0);
  if (lane == 0) bits[wid] = b;
}

// ---------------- QKV GEMM: xb[4096][1024] @ Wqkv_t[3072][1024]^T ----------------
// Epilogue scatters into Qb (pre-scaled by QSCALE) / Kb [B][H][N][64], Vt [B][H][64][N].
__global__ __launch_bounds__(256) void gemm_qkv_kernel(const u16* __restrict__ A,
                                                       const u16* __restrict__ Bt,
                                                       u16* __restrict__ Qb,
                                                       u16* __restrict__ Kb,
                                                       u16* __restrict__ Vt) {
  __shared__ u16 lA[128 * 32], lB[128 * 32];
  const int tid = threadIdx.x, lane = tid & 63, w = tid >> 6;
  const int wr = w >> 1, wc = w & 1, lrow = lane & 15, lk = lane >> 4;
  const int bm = blockIdx.y, bn = blockIdx.x;
  const int srow = tid >> 2, scol = (tid & 3) * 8;
  const u16* Arow = A + (size_t)(bm * 128 + srow) * 1024 + scol;
  const u16* Brow = Bt + (size_t)(bn * 128 + srow) * 1024 + scol;
  f32x4 acc[4][4] = {};
  for (int k0 = 0; k0 < 1024; k0 += 32) {
    uint4 a0 = *(const uint4*)(Arow + k0);
    uint4 a1 = *(const uint4*)(Arow + 64 * 1024 + k0);
    uint4 b0 = *(const uint4*)(Brow + k0);
    uint4 b1 = *(const uint4*)(Brow + 64 * 1024 + k0);
    __syncthreads();
    *(uint4*)&lA[srow * 32 + scol] = a0;
    *(uint4*)&lA[(srow + 64) * 32 + scol] = a1;
    *(uint4*)&lB[srow * 32 + scol] = b0;
    *(uint4*)&lB[(srow + 64) * 32 + scol] = b1;
    __syncthreads();
    bf16x8 af[4], bfr[4];
    for (int mi = 0; mi < 4; mi++)
      af[mi] = *(const bf16x8*)&lA[(wr * 64 + mi * 16 + lrow) * 32 + lk * 8];
    for (int ni = 0; ni < 4; ni++)
      bfr[ni] = *(const bf16x8*)&lB[(wc * 64 + ni * 16 + lrow) * 32 + lk * 8];
    for (int mi = 0; mi < 4; mi++)
      for (int ni = 0; ni < 4; ni++)
        acc[mi][ni] = __builtin_amdgcn_mfma_f32_16x16x32_bf16(af[mi], bfr[ni], acc[mi][ni], 0, 0, 0);
  }
  const int rowbase = bm * 128 + wr * 64;
  const int colbase = bn * 128 + wc * 64;
  for (int mi = 0; mi < 4; mi++)
    for (int ni = 0; ni < 4; ni++)
      for (int r = 0; r < 4; r++) {
        int row = rowbase + mi * 16 + lk * 4 + r;
        int col = colbase + ni * 16 + lrow;
        int b = row >> 11, n = row & 2047;
        int which = col >> 10, within = col & 1023;
        int h = within >> 6, d = within & 63;
        float av = acc[mi][ni][r];
        size_t bh = (size_t)(b * 16 + h);
        if (which == 0)      Qb[(bh * 2048 + n) * 64 + d] = f2b(av * QSCALE);
        else if (which == 1) Kb[(bh * 2048 + n) * 64 + d] = f2b(av);
        else                 Vt[(bh * 64 + d) * 2048 + n] = f2b(av);
      }
}

// ---------------- out-proj GEMM: attnb[4096][1024] @ Wout_t[1024][1024]^T + bias ----------------
__global__ __launch_bounds__(256) void gemm_out_kernel(const u16* __restrict__ A,
                                                       const u16* __restrict__ Bt,
                                                       const float* __restrict__ bias,
                                                       float* __restrict__ out) {
  __shared__ u16 lA[128 * 32], lB[128 * 32];
  const int tid = threadIdx.x, lane = tid & 63, w = tid >> 6;
  const int wr = w >> 1, wc = w & 1, lrow = lane & 15, lk = lane >> 4;
  const int bm = blockIdx.y, bn = blockIdx.x;
  const int srow = tid >> 2, scol = (tid & 3) * 8;
  const u16* Arow = A + (size_t)(bm * 128 + srow) * 1024 + scol;
  const u16* Brow = Bt + (size_t)(bn * 128 + srow) * 1024 + scol;
  f32x4 acc[4][4] = {};
  for (int k0 = 0; k0 < 1024; k0 += 32) {
    uint4 a0 = *(const uint4*)(Arow + k0);
    uint4 a1 = *(const uint4*)(Arow + 64 * 1024 + k0);
    uint4 b0 = *(const uint4*)(Brow + k0);
    uint4 b1 = *(const uint4*)(Brow + 64 * 1024 + k0);
    __syncthreads();
    *(uint4*)&lA[srow * 32 + scol] = a0;
    *(uint4*)&lA[(srow + 64) * 32 + scol] = a1;
    *(uint4*)&lB[srow * 32 + scol] = b0;
    *(uint4*)&lB[(srow + 64) * 32 + scol] = b1;
    __syncthreads();
    bf16x8 af[4], bfr[4];
    for (int mi = 0; mi < 4; mi++)
      af[mi] = *(const bf16x8*)&lA[(wr * 64 + mi * 16 + lrow) * 32 + lk * 8];
    for (int ni = 0; ni < 4; ni++)
      bfr[ni] = *(const bf16x8*)&lB[(wc * 64 + ni * 16 + lrow) * 32 + lk * 8];
    for (int mi = 0; mi < 4; mi++)
      for (int ni = 0; ni < 4; ni++)
        acc[mi][ni] = __builtin_amdgcn_mfma_f32_16x16x32_bf16(af[mi], bfr[ni], acc[mi][ni], 0, 0, 0);
  }
  const int rowbase = bm * 128 + wr * 64;
  const int colbase = bn * 128 + wc * 64;
  for (int mi = 0; mi < 4; mi++)
    for (int ni = 0; ni < 4; ni++)
      for (int r = 0; r < 4; r++) {
        int row = rowbase + mi * 16 + lk * 4 + r;
        int col = colbase + ni * 16 + lrow;
        out[(size_t)row * 1024 + col] = acc[mi][ni][r] + bias[col];
      }
}

// ---------------- flash attention: swapped QK^T (32x32 MFMA), LDS P-repack ----------------
// grid (16, 32), block 256 = 4 waves; wave owns 32 q-rows; kv chunks of 64.
// S^T = mfma(K, Q): lane(l31,hi) reg r holds S[kv=(r&3)+8*(r>>2)+4*hi][q=l31].
// Softmax per-lane (raw-max + deferred rescale THR=8, log2 domain) + 1 shfl_xor(32).
// P repack via per-wave LDS [kv/2][q] u32 (adjacent kv pair per word) -> contiguous
// B-frags for PV: O^T = mfma(V^T, P^T). No barriers; conflict-free LDS.
__global__ __launch_bounds__(256, 2) void attn_kernel(const u16* __restrict__ Qb,
                                                      const u16* __restrict__ Kb,
                                                      const u16* __restrict__ Vt,
                                                      const u64* __restrict__ Mb,
                                                      u16* __restrict__ attnb) {
  __shared__ u32 Plds[4][32 * 32];  // per-wave [kvpair=32][q=32]
  const int tid = threadIdx.x, lane = tid & 63, w = tid >> 6;
  const int l31 = lane & 31, hi = lane >> 5;
  const int qt = blockIdx.x, bh = blockIdx.y;
  const int h = bh & 15, b = bh >> 4;
  const int q = qt * 128 + w * 32 + l31;
  const u16* Qp = Qb + (size_t)bh * 2048 * 64;
  const u16* Kp = Kb + (size_t)bh * 2048 * 64;
  const u16* Vp = Vt + (size_t)bh * 64 * 2048;
  const u64* Mrow = Mb + (size_t)q * 32;
  u32* myP = &Plds[w][0];

  // Q B-frags: col=q=lane&31, k-half by hi; resident whole kernel
  bf16x8 qf[4];
#pragma unroll
  for (int t = 0; t < 4; t++)
    qf[t] = *(const bf16x8*)&Qp[(size_t)q * 64 + t * 16 + hi * 8];

  f32x16 acc0 = {}, acc1 = {};  // O^T: d in [0,32) / [32,64), col=q
  float m_run = -3.0e38f, lsum = 0.f;

  // K A-frags (row=kv, k-half by hi), double-buffered across chunks
  bf16x8 kA[2][4], kB[2][4];
#pragma unroll
  for (int t2 = 0; t2 < 2; t2++)
#pragma unroll
    for (int t = 0; t < 4; t++)
      kA[t2][t] = *(const bf16x8*)&Kp[(size_t)(t2 * 32 + l31) * 64 + t * 16 + hi * 8];

  auto body = [&](bf16x8 (&kc)[2][4], bf16x8 (&kn)[2][4], int j0) {
    u64 mw = Mrow[j0 >> 6];
    // V A-frags for this chunk, issued early (consumed after softmax)
    bf16x8 va[2][4];
#pragma unroll
    for (int dt = 0; dt < 2; dt++)
#pragma unroll
      for (int kk = 0; kk < 4; kk++)
        va[dt][kk] = *(const bf16x8*)&Vp[(size_t)(dt * 32 + l31) * 2048 + j0 + kk * 16 + hi * 8];

    // S^T = K·Q^T over d=64 (log2-scaled already)
    f32x16 s0 = {}, s1 = {};
    __builtin_amdgcn_s_setprio(1);
#pragma unroll
    for (int t = 0; t < 4; t++) {
      s0 = __builtin_amdgcn_mfma_f32_32x32x16_bf16(kc[0][t], qf[t], s0, 0, 0, 0);
      s1 = __builtin_amdgcn_mfma_f32_32x32x16_bf16(kc[1][t], qf[t], s1, 0, 0, 0);
    }
    __builtin_amdgcn_s_setprio(0);

    // prefetch next chunk's K frags
    if (j0 + 64 < 2048) {
#pragma unroll
      for (int t2 = 0; t2 < 2; t2++)
#pragma unroll
        for (int t = 0; t < 4; t++)
          kn[t2][t] = *(const bf16x8*)&Kp[(size_t)(j0 + 64 + t2 * 32 + l31) * 64 + t * 16 + hi * 8];
    }

    // raw row-max (mask applied later by zeroing p; same softmax), tree + partner
    float mx[8];
#pragma unroll
    for (int i = 0; i < 8; i++)
      mx[i] = fmaxf(fmaxf(s0[i], s0[i + 8]), fmaxf(s1[i], s1[i + 8]));
    float m01 = fmaxf(mx[0], mx[1]), m23 = fmaxf(mx[2], mx[3]);
    float m45 = fmaxf(mx[4], mx[5]), m67 = fmaxf(mx[6], mx[7]);
    float pm = fmaxf(fmaxf(m01, m23), fmaxf(m45, m67));
    pm = fmaxf(pm, __shfl_xor(pm, 32, 64));

    // deferred rescale (THR=8 in log2 domain -> p bounded by 256)
    if (__any(pm > m_run + 8.f)) {
      float mn = fmaxf(m_run, pm);
      float fs = exp2_fast(m_run - mn);
      m_run = mn;
      lsum *= fs;
      acc0 *= fs;
      acc1 *= fs;
    }

    // p = exp2(s - m), mask-zero, partial sums, pack kv-pairs -> LDS [kv/2][q]
    u32 w0s = (u32)(mw >> (4 * hi));          // tile0 bits, pre-shifted by 4*hi
    u32 w1s = (u32)((mw >> 32) >> (4 * hi));  // tile1 bits
#pragma unroll
    for (int p = 0; p < 8; p++) {
      const int r0 = 2 * p;
      const int sh = (r0 & 3) + 8 * (p >> 1);         // kv_local - 4*hi for reg r0
      const int wrow = (p & 1) + 4 * (p >> 1) + 2 * hi; // kv pair row (tile0)
      float a0 = exp2_fast(s0[r0] - m_run);
      float a1 = exp2_fast(s0[r0 + 1] - m_run);
      float b0 = exp2_fast(s1[r0] - m_run);
      float b1 = exp2_fast(s1[r0 + 1] - m_run);
      a0 = ((w0s >> sh) & 1u) ? a0 : 0.f;
      a1 = ((w0s >> (sh + 1)) & 1u) ? a1 : 0.f;
      b0 = ((w1s >> sh) & 1u) ? b0 : 0.f;
      b1 = ((w1s >> (sh + 1)) & 1u) ? b1 : 0.f;
      lsum += (a0 + a1) + (b0 + b1);
      myP[wrow * 32 + l31]        = (u32)f2b(a0) | ((u32)f2b(a1) << 16);
      myP[(wrow + 16) * 32 + l31] = (u32)f2b(b0) | ((u32)f2b(b1) << 16);
    }

    // PV: B-frags read back from LDS (contiguous kv per lane), A = V^T
    __builtin_amdgcn_s_setprio(1);
#pragma unroll
    for (int kk = 0; kk < 4; kk++) {
      const int base = (kk * 8 + hi * 4) * 32 + l31;
      u32 r0 = myP[base];
      u32 r1 = myP[base + 32];
      u32 r2 = myP[base + 64];
      u32 r3 = myP[base + 96];
      u32x4v pv4 = {r0, r1, r2, r3};
      bf16x8 pbf = __builtin_bit_cast(bf16x8, pv4);
      acc0 = __builtin_amdgcn_mfma_f32_32x32x16_bf16(va[0][kk], pbf, acc0, 0, 0, 0);
      acc1 = __builtin_amdgcn_mfma_f32_32x32x16_bf16(va[1][kk], pbf, acc1, 0, 0, 0);
    }
    __builtin_amdgcn_s_setprio(0);
  };

  for (int j0 = 0; j0 < 2048; j0 += 128) {
    body(kA, kB, j0);
    body(kB, kA, j0 + 64);
  }

  // finalize: partner-sum, divide, store O^T rows (d) for this q
  lsum += __shfl_xor(lsum, 32, 64);
  float inv = 1.0f / lsum;
  u16* orow = attnb + ((size_t)b * 2048 + q) * 1024 + h * 64;
#pragma unroll
  for (int rq = 0; rq < 4; rq++) {
    const int rb = rq * 4;
    {
      u32 lo = (u32)f2b(acc0[rb] * inv) | ((u32)f2b(acc0[rb + 1] * inv) << 16);
      u32 hi2 = (u32)f2b(acc0[rb + 2] * inv) | ((u32)f2b(acc0[rb + 3] * inv) << 16);
      uint2 st; st.x = lo; st.y = hi2;
      *(uint2*)(orow + 8 * rq + 4 * hi) = st;
    }
    {
      u32 lo = (u32)f2b(acc1[rb] * inv) | ((u32)f2b(acc1[rb + 1] * inv) << 16);
      u32 hi2 = (u32)f2b(acc1[rb + 2] * inv) | ((u32)f2b(acc1[rb + 3] * inv) << 16);
      uint2 st; st.x = lo; st.y = hi2;
      *(uint2*)(orow + 32 + 8 * rq + 4 * hi) = st;
    }
  }
}

extern "C" void kernel_launch(void* const* d_in, const int* in_sizes, int n_in,
                              void* d_out, int out_size, void* d_ws, size_t ws_size,
                              hipStream_t stream) {
  const float* x    = (const float*)d_in[0];
  const int*   mask = (const int*)d_in[1];
  const float* Wqkv = (const float*)d_in[2];
  const float* Wout = (const float*)d_in[3];
  const float* bout = (const float*)d_in[4];
  float* out = (float*)d_out;

  char* ws = (char*)d_ws;
  // layout (bytes): [0,8M) xb / attnb; [8M,14M) Wqkv_t, later [8M,10M) Wout_t + [10M,10.5M) maskbits;
  // [14M,22M) Qb; [22M,30M) Kb; [30M,38M) Vt
  u16* xb     = (u16*)(ws);
  u16* attnb  = xb;
  u16* Wqkv_t = (u16*)(ws + (size_t)(8u << 20));
  u16* Wout_t = Wqkv_t;
  u64* mbits  = (u64*)(ws + (size_t)(10u << 20));
  u16* Qb     = (u16*)(ws + (size_t)(14u << 20));
  u16* Kb     = (u16*)(ws + (size_t)(22u << 20));
  u16* Vt     = (u16*)(ws + (size_t)(30u << 20));

  cast_bf16_kernel<<<4096, 256, 0, stream>>>(x, xb, 4096 * 1024 / 4);
  transpose_cast_kernel<<<dim3(96, 32), dim3(32, 8), 0, stream>>>(Wqkv, Wqkv_t, 1024, 3072);
  gemm_qkv_kernel<<<dim3(24, 32), 256, 0, stream>>>(xb, Wqkv_t, Qb, Kb, Vt);
  transpose_cast_kernel<<<dim3(32, 32), dim3(32, 8), 0, stream>>>(Wout, Wout_t, 1024, 1024);
  maskbits_kernel<<<16384, 256, 0, stream>>>(mask, mbits);
  attn_kernel<<<dim3(16, 32), 256, 0, stream>>>(Qb, Kb, Vt, mbits, attnb);
  gemm_out_kernel<<<dim3(8, 32), 256, 0, stream>>>(attnb, Wout_t, bout, out);
}